// Round 8
// baseline (1082.869 us; speedup 1.0000x reference)
//
#include <hip/hip_runtime.h>

// MPALayer (HAN-style): P=3 metapath GATs + semantic attention.
// Inputs/out FLOAT32; edges int32. Path-serial to fit ws.
// R7->R8: phase_a+phase_b fused into edge_agg (block per dst): cooperative
// m/s softmax passes (32-way MLP), aggregation unrolled x4 for gather MLP.
// Deletes the 12.8 MB num round-trip and one kernel launch per path.

#define N_NODES 50000
#define N_EDGES 400000
#define N_PATHS 3
#define DIN     128
#define NH      8
#define NO      32
#define NC      256   // NH*NO
#define HID     128

__device__ __forceinline__ float bf2f(unsigned short u) {
    return __uint_as_float(((unsigned int)u) << 16);
}
__device__ __forceinline__ unsigned short f2bf(float f) {
    unsigned int u = __float_as_uint(f);
    unsigned int r = u + 0x7FFFu + ((u >> 16) & 1u);   // RNE
    return (unsigned short)(r >> 16);
}
__device__ __forceinline__ float leaky(float x) {
    return (x >= 0.f) ? x : 0.2f * x;
}

// ------------------------------------------------- node GEMM h = feat @ W_p
// grid ceil(N/64), block 256. Thread = (node-pair g, head hd): 2 nodes x 32 ch.
// W-tile reads rotation-ordered (conflict-free, R7).
__global__ __launch_bounds__(256) void gemm_node(
    const float* __restrict__ feat, const float* __restrict__ Ws,
    const float* __restrict__ al, const float* __restrict__ ar,
    unsigned short* __restrict__ hbuf, float* __restrict__ el,
    float* __restrict__ er, int p) {
    int tile = blockIdx.x * 64;
    int t = threadIdx.x;
    int hd = t & 7;
    int g  = t >> 3;                    // 0..31 -> node pair
    int ln0 = g * 2, ln1 = ln0 + 1;

    __shared__ float fs[64][36];        // 64 nodes x 32 k (pad 32->36)
    __shared__ float wls[32 * 256];     // 32 KiB

    float acc0[32], acc1[32];
#pragma unroll
    for (int o = 0; o < 32; ++o) { acc0[o] = 0.f; acc1[o] = 0.f; }

    const float* wsrc_base = Ws + (size_t)p * DIN * NC;

    for (int k0 = 0; k0 < DIN; k0 += 32) {
        const float4* wsrc = (const float4*)(wsrc_base + (size_t)k0 * NC);
        float4* wdst = (float4*)wls;
#pragma unroll
        for (int i = 0; i < 8; ++i)
            wdst[i * 256 + t] = wsrc[i * 256 + t];
#pragma unroll
        for (int i = 0; i < 2; ++i) {
            int q = i * 256 + t;        // 0..511 float4 slots
            int node = q >> 3;
            int kq = (q & 7) * 4;
            int n = tile + node;
            float4 v = make_float4(0.f, 0.f, 0.f, 0.f);
            if (n < N_NODES)
                v = *(const float4*)(feat + (size_t)n * DIN + k0 + kq);
            fs[node][kq + 0] = v.x; fs[node][kq + 1] = v.y;
            fs[node][kq + 2] = v.z; fs[node][kq + 3] = v.w;
        }
        __syncthreads();

        for (int kk = 0; kk < 32; ++kk) {
            float a0 = fs[ln0][kk];
            float a1 = fs[ln1][kk];
            const float4* wr = (const float4*)(wls + kk * 256 + hd * 32);
#pragma unroll
            for (int qq = 0; qq < 8; ++qq) {
                int q = (qq + hd) & 7;          // rotated visit order
                float4 w = wr[q];
                acc0[qq*4+0] += a0 * w.x; acc0[qq*4+1] += a0 * w.y;
                acc0[qq*4+2] += a0 * w.z; acc0[qq*4+3] += a0 * w.w;
                acc1[qq*4+0] += a1 * w.x; acc1[qq*4+1] += a1 * w.y;
                acc1[qq*4+2] += a1 * w.z; acc1[qq*4+3] += a1 * w.w;
            }
        }
        __syncthreads();
    }

    // acc[qq*4+j] holds within-head channel o = ((qq+hd)&7)*4 + j
    const float* alp = al + (p * NH + hd) * NO;
    const float* arp = ar + (p * NH + hd) * NO;
    float el0 = 0.f, er0 = 0.f, el1 = 0.f, er1 = 0.f;
#pragma unroll
    for (int qq = 0; qq < 8; ++qq) {
        int q = (qq + hd) & 7;
#pragma unroll
        for (int j = 0; j < 4; ++j) {
            float a = alp[q*4+j], r = arp[q*4+j];
            el0 += acc0[qq*4+j] * a; er0 += acc0[qq*4+j] * r;
            el1 += acc1[qq*4+j] * a; er1 += acc1[qq*4+j] * r;
        }
    }
    int n0 = tile + ln0, n1 = tile + ln1;
    if (n0 < N_NODES) {
        unsigned short* hb = hbuf + (size_t)n0 * NC + hd * 32;
#pragma unroll
        for (int qq = 0; qq < 8; ++qq) {
            int q = (qq + hd) & 7;
            uint2 pk;
            pk.x = (unsigned int)f2bf(acc0[qq*4+0]) | ((unsigned int)f2bf(acc0[qq*4+1]) << 16);
            pk.y = (unsigned int)f2bf(acc0[qq*4+2]) | ((unsigned int)f2bf(acc0[qq*4+3]) << 16);
            *(uint2*)(hb + q*4) = pk;
        }
        el[(size_t)n0 * NH + hd] = el0;
        er[(size_t)n0 * NH + hd] = er0;
    }
    if (n1 < N_NODES) {
        unsigned short* hb = hbuf + (size_t)n1 * NC + hd * 32;
#pragma unroll
        for (int qq = 0; qq < 8; ++qq) {
            int q = (qq + hd) & 7;
            uint2 pk;
            pk.x = (unsigned int)f2bf(acc1[qq*4+0]) | ((unsigned int)f2bf(acc1[qq*4+1]) << 16);
            pk.y = (unsigned int)f2bf(acc1[qq*4+2]) | ((unsigned int)f2bf(acc1[qq*4+3]) << 16);
            *(uint2*)(hb + q*4) = pk;
        }
        el[(size_t)n1 * NH + hd] = el1;
        er[(size_t)n1 * NH + hd] = er1;
    }
}

// ------------------------------------------------------------- degree count
__global__ void count_deg(const int* __restrict__ edges_p, int* __restrict__ deg) {
    int e = blockIdx.x * 256 + threadIdx.x;
    if (e >= N_EDGES) return;
    int dst = edges_p[N_EDGES + e];
    atomicAdd(&deg[dst], 1);
}

// ------------------------------------------------------- 3-phase exclusive scan
__global__ void scan_chunk(const int* __restrict__ deg, int* __restrict__ offs,
                           int* __restrict__ ctot) {
    int i = blockIdx.x * 256 + threadIdx.x;
    __shared__ int s[256];
    int v = (i < N_NODES) ? deg[i] : 0;
    int orig = v;
    for (int off = 1; off < 256; off <<= 1) {
        s[threadIdx.x] = v; __syncthreads();
        int add = (threadIdx.x >= off) ? s[threadIdx.x - off] : 0;
        __syncthreads();
        v += add;
    }
    if (i < N_NODES) offs[i] = v - orig;
    if (threadIdx.x == 255) ctot[blockIdx.x] = v;
}

__global__ void scan_tot(const int* __restrict__ ctot, int* __restrict__ cbase, int nch) {
    int t = threadIdx.x;
    __shared__ int s[256];
    int v = (t < nch) ? ctot[t] : 0;
    int orig = v;
    for (int off = 1; off < 256; off <<= 1) {
        s[t] = v; __syncthreads();
        int add = (t >= off) ? s[t - off] : 0;
        __syncthreads();
        v += add;
    }
    cbase[t] = v - orig;
}

__global__ void add_base(int* __restrict__ offs, const int* __restrict__ cbase) {
    int i = blockIdx.x * 256 + threadIdx.x;
    if (i < N_NODES) offs[i] += cbase[blockIdx.x];
}

// ------------------------------------------------------------------ CSR fill
__global__ void fill_csr(const int* __restrict__ edges_p, const int* __restrict__ offs,
                         int* __restrict__ cursor, int* __restrict__ csr) {
    int e = blockIdx.x * 256 + threadIdx.x;
    if (e >= N_EDGES) return;
    int src = edges_p[e], dst = edges_p[N_EDGES + e];
    int pos = atomicAdd(&cursor[dst], 1);
    csr[offs[dst] + pos] = src;
}

// --------- fused edge softmax + aggregation: block per dst, 256 threads.
// Pass 1/2 (cooperative, 32 j-lanes x 8 heads): per-head max, then sum of
// exps -> m[8], inv_s[8] in LDS. Pass 3 (thread=channel): recompute alpha
// per thread (el broadcast + expf), aggregate h rows, unroll x4 for MLP.
__global__ __launch_bounds__(256) void edge_agg(
    const int* __restrict__ csr, const int* __restrict__ offs, const int* __restrict__ deg,
    const float* __restrict__ el, const float* __restrict__ er,
    const unsigned short* __restrict__ hbuf, const float* __restrict__ bias,
    float* __restrict__ zbuf, int p) {
    int dst = blockIdx.x;
    int t = threadIdx.x;
    int off = offs[dst];
    int d   = deg[dst];
    const int* cp = csr + off;

    __shared__ float red[32][8];
    __shared__ float mh_s[8];
    __shared__ float is_s[8];

    int jl  = t >> 3;       // 0..31 strided edge lane
    int hd8 = t & 7;        // head
    float erv8 = er[(size_t)dst * NH + hd8];

    // pass 1: per-head max
    float mloc = -1e30f;
    for (int j = jl; j < d; j += 32) {
        int src = cp[j];
        mloc = fmaxf(mloc, leaky(el[src * NH + hd8] + erv8));
    }
    red[jl][hd8] = mloc;
    __syncthreads();
#pragma unroll
    for (int o = 16; o > 0; o >>= 1) {
        if (jl < o) red[jl][hd8] = fmaxf(red[jl][hd8], red[jl + o][hd8]);
        __syncthreads();
    }
    if (t < 8) mh_s[t] = red[0][t];
    __syncthreads();

    // pass 2: per-head sum of exps
    float mh8 = mh_s[hd8];
    float sloc = 0.f;
    for (int j = jl; j < d; j += 32) {
        int src = cp[j];
        sloc += expf(leaky(el[src * NH + hd8] + erv8) - mh8);
    }
    red[jl][hd8] = sloc;
    __syncthreads();
#pragma unroll
    for (int o = 16; o > 0; o >>= 1) {
        if (jl < o) red[jl][hd8] += red[jl + o][hd8];
        __syncthreads();
    }
    if (t < 8) is_s[t] = (d > 0) ? 1.0f / red[0][t] : 0.f;
    __syncthreads();

    // pass 3: aggregate (thread = channel)
    int c = t;
    int hd = c >> 5;
    float mh  = mh_s[hd];
    float isv = is_s[hd];
    float erv = er[(size_t)dst * NH + hd];
    float acc = 0.f;
    int j = 0;
    for (; j + 4 <= d; j += 4) {
        int s0 = cp[j], s1 = cp[j+1], s2 = cp[j+2], s3 = cp[j+3];
        float x0 = el[s0 * NH + hd], x1 = el[s1 * NH + hd];
        float x2 = el[s2 * NH + hd], x3 = el[s3 * NH + hd];
        float h0 = bf2f(hbuf[(size_t)s0 * NC + c]);
        float h1 = bf2f(hbuf[(size_t)s1 * NC + c]);
        float h2 = bf2f(hbuf[(size_t)s2 * NC + c]);
        float h3 = bf2f(hbuf[(size_t)s3 * NC + c]);
        float a0 = expf(leaky(x0 + erv) - mh) * isv;
        float a1 = expf(leaky(x1 + erv) - mh) * isv;
        float a2 = expf(leaky(x2 + erv) - mh) * isv;
        float a3 = expf(leaky(x3 + erv) - mh) * isv;
        acc += a0 * h0 + a1 * h1 + a2 * h2 + a3 * h3;
    }
    for (; j < d; ++j) {
        int s0 = cp[j];
        float a0 = expf(leaky(el[s0 * NH + hd] + erv) - mh) * isv;
        acc += a0 * bf2f(hbuf[(size_t)s0 * NC + c]);
    }
    float zv = acc + bias[p * NC + c];
    zv = (zv > 0.f) ? zv : expm1f(zv);
    zbuf[((size_t)p * N_NODES + dst) * NC + c] = zv;
}

// -------------- semantic: LDS-tiled GEMM, 64 nodes/block, K-chunks of 64.
__global__ __launch_bounds__(256) void semantic(
    const float* __restrict__ zbuf, const float* __restrict__ W1,
    const float* __restrict__ b1, const float* __restrict__ w2,
    float* __restrict__ wpart) {
    int p = blockIdx.y;
    int n0 = blockIdx.x * 64;
    int t = threadIdx.x;
    int pair = t >> 3;          // 0..31 -> local nodes pair*2, pair*2+1
    int h = t & 7;
    int j0 = h * 16;            // 16 hidden units per thread
    int rot = h >> 1;           // 0..3

    __shared__ float zs[64][68];        // 17.0 KiB (pad 64->68)
    __shared__ float w1s[64 * 128];     // 32 KiB
    __shared__ float red[64][8];        // 2 KiB

    float acc0[16], acc1[16];
#pragma unroll
    for (int i = 0; i < 16; ++i) { acc0[i] = 0.f; acc1[i] = 0.f; }

    int ln0 = pair * 2, ln1 = ln0 + 1;

    for (int k0 = 0; k0 < NC; k0 += 64) {
        const float4* wsrc = (const float4*)(W1 + (size_t)k0 * HID);
        float4* wdst = (float4*)w1s;
#pragma unroll
        for (int i = 0; i < 8; ++i)
            wdst[i * 256 + t] = wsrc[i * 256 + t];
#pragma unroll
        for (int i = 0; i < 4; ++i) {
            int q = i * 256 + t;        // 0..1023 float4 slots
            int node = q >> 4;
            int kq = (q & 15) * 4;
            int n = n0 + node;
            float4 v = make_float4(0.f, 0.f, 0.f, 0.f);
            if (n < N_NODES)
                v = *(const float4*)(zbuf + ((size_t)p * N_NODES + n) * NC + k0 + kq);
            zs[node][kq + 0] = v.x; zs[node][kq + 1] = v.y;
            zs[node][kq + 2] = v.z; zs[node][kq + 3] = v.w;
        }
        __syncthreads();

        for (int kk = 0; kk < 64; ++kk) {
            float z0 = zs[ln0][kk];
            float z1 = zs[ln1][kk];
            const float4* wr = (const float4*)(w1s + kk * 128 + j0);
#pragma unroll
            for (int ii = 0; ii < 4; ++ii) {
                int i = (ii + rot) & 3;         // rotated visit order
                float4 w = wr[i];
                acc0[ii*4+0] += z0 * w.x; acc0[ii*4+1] += z0 * w.y;
                acc0[ii*4+2] += z0 * w.z; acc0[ii*4+3] += z0 * w.w;
                acc1[ii*4+0] += z1 * w.x; acc1[ii*4+1] += z1 * w.y;
                acc1[ii*4+2] += z1 * w.z; acc1[ii*4+3] += z1 * w.w;
            }
        }
        __syncthreads();
    }

    // acc[ii*4+c] holds hidden unit j = j0 + ((ii+rot)&3)*4 + c
    float s0 = 0.f, s1 = 0.f;
#pragma unroll
    for (int ii = 0; ii < 4; ++ii) {
        int i = (ii + rot) & 3;
#pragma unroll
        for (int c = 0; c < 4; ++c) {
            int j = j0 + i*4 + c;
            float b = b1[j], wv = w2[j];
            s0 += tanhf(acc0[ii*4+c] + b) * wv;
            s1 += tanhf(acc1[ii*4+c] + b) * wv;
        }
    }
    red[ln0][h] = s0;
    red[ln1][h] = s1;
    __syncthreads();
    if (t < 64) {
        float s = 0.f;
#pragma unroll
        for (int g2 = 0; g2 < 8; ++g2) s += red[t][g2];
        if (n0 + t >= N_NODES) s = 0.f;     // mask tail nodes
        for (int o = 32; o > 0; o >>= 1)
            s += __shfl_down(s, o, 64);
        if (t == 0) atomicAdd(&wpart[p * 256 + (blockIdx.x & 255)], s);
    }
}

// ------------------------------------------------------------- beta (softmax)
__global__ void compute_beta(const float* __restrict__ wpart, float* __restrict__ beta) {
    __shared__ float s[256];
    int t = threadIdx.x;
    float m[N_PATHS];
    for (int p = 0; p < N_PATHS; ++p) {
        s[t] = wpart[p * 256 + t];
        __syncthreads();
        for (int off = 128; off > 0; off >>= 1) {
            if (t < off) s[t] += s[t + off];
            __syncthreads();
        }
        m[p] = s[0] / (float)N_NODES;
        __syncthreads();
    }
    if (t == 0) {
        float mx = fmaxf(m[0], fmaxf(m[1], m[2]));
        float e0 = expf(m[0] - mx), e1 = expf(m[1] - mx), e2 = expf(m[2] - mx);
        float inv = 1.f / (e0 + e1 + e2);
        beta[0] = e0 * inv; beta[1] = e1 * inv; beta[2] = e2 * inv;
    }
}

// ----------------------------------------------------------------- final mix
__global__ __launch_bounds__(256) void final_mix(
    const float* __restrict__ zbuf, const float* __restrict__ beta,
    float* __restrict__ out) {
    int n = blockIdx.x;
    int c = threadIdx.x;
    float b0 = beta[0], b1 = beta[1], b2 = beta[2];
    size_t stride = (size_t)N_NODES * NC;
    size_t idx = (size_t)n * NC + c;
    out[idx] = b0 * zbuf[idx] + b1 * zbuf[idx + stride]
             + b2 * zbuf[idx + 2 * stride];
}

extern "C" void kernel_launch(void* const* d_in, const int* in_sizes, int n_in,
                              void* d_out, int out_size, void* d_ws, size_t ws_size,
                              hipStream_t stream) {
    const float* feat  = (const float*)d_in[0];
    const int*   edges = (const int*)d_in[1];
    const float* Ws    = (const float*)d_in[2];
    const float* al    = (const float*)d_in[3];
    const float* ar    = (const float*)d_in[4];
    const float* bias  = (const float*)d_in[5];
    const float* W1    = (const float*)d_in[6];
    const float* b1    = (const float*)d_in[7];
    const float* w2    = (const float*)d_in[8];
    float* out = (float*)d_out;

    // ---- workspace layout (256B-aligned slabs), ~185 MB total
    size_t off = 0;
    auto alloc = [&](size_t bytes) { size_t o = off; off += (bytes + 255) & ~(size_t)255; return o; };
    size_t zbuf_o  = alloc((size_t)N_PATHS * N_NODES * NC * 4);  // 153.6 MB
    size_t hbuf_o  = alloc((size_t)N_NODES * NC * 2);            // 25.6 MB (per path, bf16)
    size_t el_o    = alloc((size_t)N_NODES * NH * 4);
    size_t er_o    = alloc((size_t)N_NODES * NH * 4);
    size_t csr_o   = alloc((size_t)N_EDGES * 4);
    size_t offs_o  = alloc((size_t)N_NODES * 4);
    size_t ctot_o  = alloc(256 * 4);
    size_t cbase_o = alloc(256 * 4);
    size_t beta_o  = alloc(256);
    size_t deg_o    = alloc((size_t)N_NODES * 4);
    size_t cursor_o = alloc((size_t)N_NODES * 4);
    size_t zend_o   = off;
    size_t wpart_o  = alloc((size_t)N_PATHS * 256 * 4);
    size_t total = off;
    if (ws_size < total) return;  // fail loudly (zero output)

    char* ws = (char*)d_ws;
    float*          zbuf  = (float*)(ws + zbuf_o);
    unsigned short* hbuf  = (unsigned short*)(ws + hbuf_o);
    float* el    = (float*)(ws + el_o);
    float* er    = (float*)(ws + er_o);
    int*   csr   = (int*)(ws + csr_o);
    int*   offs  = (int*)(ws + offs_o);
    int*   ctot  = (int*)(ws + ctot_o);
    int*   cbase = (int*)(ws + cbase_o);
    float* beta  = (float*)(ws + beta_o);
    int*   deg   = (int*)(ws + deg_o);
    int*   cursor= (int*)(ws + cursor_o);
    float* wpart = (float*)(ws + wpart_o);

    const int NCH = (N_NODES + 255) / 256;   // 196 scan chunks

    hipMemsetAsync(ws + wpart_o, 0, (size_t)N_PATHS * 256 * 4, stream);

    for (int p = 0; p < N_PATHS; ++p) {
        const int* edges_p = edges + (size_t)p * 2 * N_EDGES;
        hipMemsetAsync(ws + deg_o, 0, zend_o - deg_o, stream);  // deg + cursor
        gemm_node<<<(N_NODES + 63) / 64, 256, 0, stream>>>(
            feat, Ws, al, ar, hbuf, el, er, p);
        count_deg<<<(N_EDGES + 255) / 256, 256, 0, stream>>>(edges_p, deg);
        scan_chunk<<<NCH, 256, 0, stream>>>(deg, offs, ctot);
        scan_tot<<<1, 256, 0, stream>>>(ctot, cbase, NCH);
        add_base<<<NCH, 256, 0, stream>>>(offs, cbase);
        fill_csr<<<(N_EDGES + 255) / 256, 256, 0, stream>>>(edges_p, offs, cursor, csr);
        edge_agg<<<N_NODES, 256, 0, stream>>>(csr, offs, deg, el, er, hbuf, bias, zbuf, p);
    }
    semantic<<<dim3((N_NODES + 63) / 64, N_PATHS), 256, 0, stream>>>(
        zbuf, W1, b1, w2, wpart);
    compute_beta<<<1, 256, 0, stream>>>(wpart, beta);
    final_mix<<<N_NODES, 256, 0, stream>>>(zbuf, beta, out);
}